// Round 1
// baseline (725.771 us; speedup 1.0000x reference)
//
#include <hip/hip_runtime.h>

// Problem constants (from reference): N=1048576, C=128, S=4.
#define NCLS 128
#define NSUB 4
#define NGRP (NCLS * NSUB)   // 512 (y,s) groups
#define MAIN_BLOCKS 2048
#define MAIN_THREADS 256     // 4 waves/block
#define HIST_BLOCKS 256
#define HIST_THREADS 256

// ws layout:
//   [0,    2048)  int   counts[512]
//   [2048, 4096)  float recip[512]
//   [8192, 8192+2048*8) double partials[MAIN_BLOCKS]

__global__ void orl_zero_kernel(int* __restrict__ counts) {
    int i = threadIdx.x;
    if (i < NGRP) counts[i] = 0;
}

__global__ void orl_hist_kernel(const int* __restrict__ tgt,
                                const int* __restrict__ sub,
                                int* __restrict__ counts, int n4) {
    __shared__ int h[NGRP];
    for (int i = threadIdx.x; i < NGRP; i += blockDim.x) h[i] = 0;
    __syncthreads();
    const int tid = blockIdx.x * blockDim.x + threadIdx.x;
    const int stride = gridDim.x * blockDim.x;
    const int4* t4 = (const int4*)tgt;
    const int4* s4 = (const int4*)sub;
    for (int i = tid; i < n4; i += stride) {
        int4 t = t4[i];
        int4 s = s4[i];
        atomicAdd(&h[(t.x << 2) | s.x], 1);
        atomicAdd(&h[(t.y << 2) | s.y], 1);
        atomicAdd(&h[(t.z << 2) | s.z], 1);
        atomicAdd(&h[(t.w << 2) | s.w], 1);
    }
    __syncthreads();
    for (int i = threadIdx.x; i < NGRP; i += blockDim.x) {
        int v = h[i];
        if (v) atomicAdd(&counts[i], v);
    }
}

__global__ void orl_recip_kernel(const int* __restrict__ counts,
                                 float* __restrict__ recip) {
    int i = threadIdx.x;
    if (i < NGRP) {
        int c = counts[i];
        recip[i] = c ? (1.0f / (float)c) : 0.0f;  // empty group never referenced
    }
}

// One wave per row: lane i holds cols {2i, 2i+1} as float2 (512B coalesced/row).
__global__ void orl_main_kernel(const float* __restrict__ logits,
                                const int* __restrict__ tgt,
                                const int* __restrict__ sub,
                                const float* __restrict__ recip,
                                double* __restrict__ partials, int n) {
    const int lane  = threadIdx.x & 63;
    const int wid   = threadIdx.x >> 6;
    const int gwave = (blockIdx.x * blockDim.x + threadIdx.x) >> 6;
    const int nwave = (gridDim.x * blockDim.x) >> 6;

    float local = 0.0f;
    for (int row = gwave; row < n; row += nwave) {
        const float2 v = reinterpret_cast<const float2*>(logits)[(size_t)row * 64 + lane];
        // wave max-reduce
        float m = fmaxf(v.x, v.y);
        #pragma unroll
        for (int off = 32; off; off >>= 1) m = fmaxf(m, __shfl_xor(m, off));
        // wave sum-reduce of exp(x - m)
        float e = __expf(v.x - m) + __expf(v.y - m);
        #pragma unroll
        for (int off = 32; off; off >>= 1) e += __shfl_xor(e, off);
        // target logit: element (t&1) of lane (t>>1)
        int t = tgt[row];
        float cand = (t & 1) ? v.y : v.x;
        float tv = __shfl(cand, t >> 1);
        float ps = m + __logf(e) - tv;           // logsumexp - logit[target]
        int g = (t << 2) | sub[row];
        local += ps * recip[g];                   // uniform across the wave
    }

    __shared__ float wsum[MAIN_THREADS / 64];
    if (lane == 0) wsum[wid] = local;             // local is wave-uniform
    __syncthreads();
    if (threadIdx.x == 0) {
        double b = 0.0;
        #pragma unroll
        for (int w = 0; w < MAIN_THREADS / 64; ++w) b += (double)wsum[w];
        partials[blockIdx.x] = b;
    }
}

__global__ void orl_final_kernel(const double* __restrict__ partials, int nb,
                                 float* __restrict__ out) {
    double v = 0.0;
    for (int i = threadIdx.x; i < nb; i += blockDim.x) v += partials[i];
    #pragma unroll
    for (int off = 32; off; off >>= 1) v += __shfl_xor(v, off);
    __shared__ double sm[4];
    const int lane = threadIdx.x & 63, wid = threadIdx.x >> 6;
    if (lane == 0) sm[wid] = v;
    __syncthreads();
    if (threadIdx.x == 0) out[0] = (float)(sm[0] + sm[1] + sm[2] + sm[3]);
}

extern "C" void kernel_launch(void* const* d_in, const int* in_sizes, int n_in,
                              void* d_out, int out_size, void* d_ws, size_t ws_size,
                              hipStream_t stream) {
    const float* logits = (const float*)d_in[0];
    const int*   tgt    = (const int*)d_in[1];
    const int*   sub    = (const int*)d_in[2];
    const int n = in_sizes[1];

    int*    counts   = (int*)d_ws;
    float*  recip    = (float*)((char*)d_ws + NGRP * sizeof(int));
    double* partials = (double*)((char*)d_ws + 8192);
    float*  out      = (float*)d_out;

    orl_zero_kernel<<<1, NGRP, 0, stream>>>(counts);
    orl_hist_kernel<<<HIST_BLOCKS, HIST_THREADS, 0, stream>>>(tgt, sub, counts, n / 4);
    orl_recip_kernel<<<1, NGRP, 0, stream>>>(counts, recip);
    orl_main_kernel<<<MAIN_BLOCKS, MAIN_THREADS, 0, stream>>>(logits, tgt, sub, recip, partials, n);
    orl_final_kernel<<<1, 256, 0, stream>>>(partials, MAIN_BLOCKS, out);
}

// Round 5
// 688.963 us; speedup vs baseline: 1.0534x; 1.0534x over previous
//
#include <hip/hip_runtime.h>

// Problem: N=1048576 rows, C=128 classes, S=4 subgroups.
// loss = sum_i CE_i / count[group_i],  group = t*4 + s.
//
// Pipeline: zero(counts) -> hist (LDS-privatized) -> main -> final.
// Main: 8 lanes per row, 8 rows per wave. Target logit extracted via a
// masked-sum fused into the denominator reduction (no dynamic-lane shuffle).

#define NCLS 128
#define NSUB 4
#define NGRP (NCLS * NSUB)   // 512
#define MAIN_BLOCKS 2048
#define MAIN_THREADS 256     // 4 waves/block
#define HIST_BLOCKS 256
#define HIST_THREADS 256

// ws layout:
//   [0, 2048)              int    counts[512]
//   [8192, 8192+2048*8)    double partials[MAIN_BLOCKS]

__global__ void orl_zero_kernel(int* __restrict__ counts) {
    int i = threadIdx.x;
    if (i < NGRP) counts[i] = 0;
}

__global__ void orl_hist_kernel(const int* __restrict__ tgt,
                                const int* __restrict__ sub,
                                int* __restrict__ counts, int n4) {
    __shared__ int h[NGRP];
    for (int i = threadIdx.x; i < NGRP; i += blockDim.x) h[i] = 0;
    __syncthreads();
    const int tid = blockIdx.x * blockDim.x + threadIdx.x;
    const int stride = gridDim.x * blockDim.x;
    const int4* t4 = (const int4*)tgt;
    const int4* s4 = (const int4*)sub;
    for (int i = tid; i < n4; i += stride) {
        int4 t = t4[i];
        int4 s = s4[i];
        atomicAdd(&h[(t.x << 2) | s.x], 1);
        atomicAdd(&h[(t.y << 2) | s.y], 1);
        atomicAdd(&h[(t.z << 2) | s.z], 1);
        atomicAdd(&h[(t.w << 2) | s.w], 1);
    }
    __syncthreads();
    for (int i = threadIdx.x; i < NGRP; i += blockDim.x) {
        int v = h[i];
        if (v) atomicAdd(&counts[i], v);
    }
}

// 8 lanes/row, 8 rows/wave. Lane sl of group grp holds cols
// {p*32 + sl*4 + k : p in 0..3, k in 0..3} of row (rb*8 + grp).
__global__ void orl_main_kernel(const float* __restrict__ logits,
                                const int* __restrict__ tgt,
                                const int* __restrict__ sub,
                                const int* __restrict__ counts,
                                double* __restrict__ partials, int n8) {
    const int lane = threadIdx.x & 63;
    const int sl   = lane & 7;    // sub-lane within row group
    const int grp  = lane >> 3;   // which of 8 rows this wave-iter
    const int wid  = threadIdx.x >> 6;
    const int gw   = (blockIdx.x * blockDim.x + threadIdx.x) >> 6;
    const int nw   = (gridDim.x * blockDim.x) >> 6;
    const int sl4  = sl << 2;

    float local = 0.0f;
    for (int rb = gw; rb < n8; rb += nw) {
        const int row = (rb << 3) + grp;
        const float4* rp = reinterpret_cast<const float4*>(logits + ((size_t)row << 7));
        // 4 coalesced 16B loads: wave covers 8 rows x 512B.
        float4 A = rp[sl];
        float4 B = rp[sl + 8];
        float4 C = rp[sl + 16];
        float4 D = rp[sl + 24];
        const int t = tgt[row];
        const int s = sub[row];

        float v[16] = {A.x, A.y, A.z, A.w, B.x, B.y, B.z, B.w,
                       C.x, C.y, C.z, C.w, D.x, D.y, D.z, D.w};
        // lane-local max
        float m = v[0];
        #pragma unroll
        for (int k = 1; k < 16; ++k) m = fmaxf(m, v[k]);
        // 8-lane max reduce (3 steps)
        m = fmaxf(m, __shfl_xor(m, 1));
        m = fmaxf(m, __shfl_xor(m, 2));
        m = fmaxf(m, __shfl_xor(m, 4));

        // fused: exp-sum + masked target pick (col == t contributes v)
        const int tt = t - sl4;   // element k matches iff (k>>2)*32 + (k&3) == tt
        float e = 0.0f, tv = 0.0f;
        #pragma unroll
        for (int k = 0; k < 16; ++k) {
            e += __expf(v[k] - m);
            const int code = ((k >> 2) << 5) + (k & 3);
            tv = (code == tt) ? v[k] : tv;
        }
        // 8-lane sum reduce of (e, tv)
        e  += __shfl_xor(e, 1);  tv += __shfl_xor(tv, 1);
        e  += __shfl_xor(e, 2);  tv += __shfl_xor(tv, 2);
        e  += __shfl_xor(e, 4);  tv += __shfl_xor(tv, 4);

        const float ps = m + __logf(e) - tv;             // -log p[t]
        const int cnt = counts[(t << 2) | s];
        const float w = ps / (float)cnt;                 // f32 div, matches ref
        if (sl == 0) local += w;
    }

    // full-wave sum (only sl==0 lanes carry values)
    #pragma unroll
    for (int off = 32; off; off >>= 1) local += __shfl_xor(local, off);

    __shared__ float wsum[MAIN_THREADS / 64];
    if ((threadIdx.x & 63) == 0) wsum[wid] = local;
    __syncthreads();
    if (threadIdx.x == 0) {
        double b = 0.0;
        #pragma unroll
        for (int w = 0; w < MAIN_THREADS / 64; ++w) b += (double)wsum[w];
        partials[blockIdx.x] = b;
    }
}

__global__ void orl_final_kernel(const double* __restrict__ partials, int nb,
                                 float* __restrict__ out) {
    double v = 0.0;
    for (int i = threadIdx.x; i < nb; i += blockDim.x) v += partials[i];
    #pragma unroll
    for (int off = 32; off; off >>= 1) v += __shfl_xor(v, off);
    __shared__ double sm[4];
    const int lane = threadIdx.x & 63, wid = threadIdx.x >> 6;
    if (lane == 0) sm[wid] = v;
    __syncthreads();
    if (threadIdx.x == 0) out[0] = (float)(sm[0] + sm[1] + sm[2] + sm[3]);
}

extern "C" void kernel_launch(void* const* d_in, const int* in_sizes, int n_in,
                              void* d_out, int out_size, void* d_ws, size_t ws_size,
                              hipStream_t stream) {
    const float* logits = (const float*)d_in[0];
    const int*   tgt    = (const int*)d_in[1];
    const int*   sub    = (const int*)d_in[2];
    const int n = in_sizes[1];

    int*    counts   = (int*)d_ws;
    double* partials = (double*)((char*)d_ws + 8192);
    float*  out      = (float*)d_out;

    orl_zero_kernel<<<1, NGRP, 0, stream>>>(counts);
    orl_hist_kernel<<<HIST_BLOCKS, HIST_THREADS, 0, stream>>>(tgt, sub, counts, n / 4);
    orl_main_kernel<<<MAIN_BLOCKS, MAIN_THREADS, 0, stream>>>(logits, tgt, sub, counts, partials, n >> 3);
    orl_final_kernel<<<1, 256, 0, stream>>>(partials, MAIN_BLOCKS, out);
}

// Round 6
// 688.333 us; speedup vs baseline: 1.0544x; 1.0009x over previous
//
#include <hip/hip_runtime.h>

// Problem: N=1048576 rows, C=128 classes, S=4 subgroups.
// loss = sum_i CE_i / count[group_i],  group = t*4 + s.
//
// Pipeline: zero(counts) -> hist (LDS-privatized) -> main -> final.
// Main: 8 lanes per row, 8 rows per wave; target logit via masked-sum fused
// into the denominator reduction (no dynamic-lane shuffle).
// R6: index loads (tgt/sub/counts) hoisted ahead of the float4 logits loads
// so their latency hides under the stream; __launch_bounds__ guard on main.
// Timed-window note: harness re-poison (2.1 GiB fill ~330us) + d_in restore
// (~230us) are inside the captured graph => ~560us floor we cannot touch.

#define NCLS 128
#define NSUB 4
#define NGRP (NCLS * NSUB)   // 512
#define MAIN_BLOCKS 2048
#define MAIN_THREADS 256     // 4 waves/block
#define HIST_BLOCKS 256
#define HIST_THREADS 256

// ws layout:
//   [0, 2048)              int    counts[512]
//   [8192, 8192+2048*8)    double partials[MAIN_BLOCKS]

__global__ void orl_zero_kernel(int* __restrict__ counts) {
    int i = threadIdx.x;
    if (i < NGRP) counts[i] = 0;
}

__global__ void orl_hist_kernel(const int* __restrict__ tgt,
                                const int* __restrict__ sub,
                                int* __restrict__ counts, int n4) {
    __shared__ int h[NGRP];
    for (int i = threadIdx.x; i < NGRP; i += blockDim.x) h[i] = 0;
    __syncthreads();
    const int tid = blockIdx.x * blockDim.x + threadIdx.x;
    const int stride = gridDim.x * blockDim.x;
    const int4* t4 = (const int4*)tgt;
    const int4* s4 = (const int4*)sub;
    for (int i = tid; i < n4; i += stride) {
        int4 t = t4[i];
        int4 s = s4[i];
        atomicAdd(&h[(t.x << 2) | s.x], 1);
        atomicAdd(&h[(t.y << 2) | s.y], 1);
        atomicAdd(&h[(t.z << 2) | s.z], 1);
        atomicAdd(&h[(t.w << 2) | s.w], 1);
    }
    __syncthreads();
    for (int i = threadIdx.x; i < NGRP; i += blockDim.x) {
        int v = h[i];
        if (v) atomicAdd(&counts[i], v);
    }
}

// 8 lanes/row, 8 rows/wave. Lane sl of group grp holds cols
// {p*32 + sl*4 + k : p in 0..3, k in 0..3} of row (rb*8 + grp).
__global__ void __launch_bounds__(MAIN_THREADS, 4)
orl_main_kernel(const float* __restrict__ logits,
                const int* __restrict__ tgt,
                const int* __restrict__ sub,
                const int* __restrict__ counts,
                double* __restrict__ partials, int n8) {
    const int lane = threadIdx.x & 63;
    const int sl   = lane & 7;    // sub-lane within row group
    const int grp  = lane >> 3;   // which of 8 rows this wave-iter
    const int wid  = threadIdx.x >> 6;
    const int gw   = (blockIdx.x * blockDim.x + threadIdx.x) >> 6;
    const int nw   = (gridDim.x * blockDim.x) >> 6;
    const int sl4  = sl << 2;

    float local = 0.0f;
    for (int rb = gw; rb < n8; rb += nw) {
        const int row = (rb << 3) + grp;
        // Hoist index loads: issue BEFORE the logits loads so their latency
        // overlaps the 4KB row-block stream (they are consumed last).
        const int t = tgt[row];
        const int s = sub[row];
        const int cnt = counts[(t << 2) | s];

        const float4* rp = reinterpret_cast<const float4*>(logits + ((size_t)row << 7));
        // 4 coalesced 16B loads: wave covers 8 rows x 512B (4KB contiguous).
        float4 A = rp[sl];
        float4 B = rp[sl + 8];
        float4 C = rp[sl + 16];
        float4 D = rp[sl + 24];

        float v[16] = {A.x, A.y, A.z, A.w, B.x, B.y, B.z, B.w,
                       C.x, C.y, C.z, C.w, D.x, D.y, D.z, D.w};
        // lane-local max
        float m = v[0];
        #pragma unroll
        for (int k = 1; k < 16; ++k) m = fmaxf(m, v[k]);
        // 8-lane max reduce (3 steps)
        m = fmaxf(m, __shfl_xor(m, 1));
        m = fmaxf(m, __shfl_xor(m, 2));
        m = fmaxf(m, __shfl_xor(m, 4));

        // fused: exp-sum + masked target pick (col == t contributes v)
        const int tt = t - sl4;   // element k matches iff (k>>2)*32 + (k&3) == tt
        float e = 0.0f, tv = 0.0f;
        #pragma unroll
        for (int k = 0; k < 16; ++k) {
            e += __expf(v[k] - m);
            const int code = ((k >> 2) << 5) + (k & 3);
            tv = (code == tt) ? v[k] : tv;
        }
        // 8-lane sum reduce of (e, tv)
        e  += __shfl_xor(e, 1);  tv += __shfl_xor(tv, 1);
        e  += __shfl_xor(e, 2);  tv += __shfl_xor(tv, 2);
        e  += __shfl_xor(e, 4);  tv += __shfl_xor(tv, 4);

        const float ps = m + __logf(e) - tv;             // -log p[t]
        const float w = ps / (float)cnt;                 // f32 div, matches ref
        if (sl == 0) local += w;
    }

    // full-wave sum (only sl==0 lanes carry values)
    #pragma unroll
    for (int off = 32; off; off >>= 1) local += __shfl_xor(local, off);

    __shared__ float wsum[MAIN_THREADS / 64];
    if ((threadIdx.x & 63) == 0) wsum[wid] = local;
    __syncthreads();
    if (threadIdx.x == 0) {
        double b = 0.0;
        #pragma unroll
        for (int w = 0; w < MAIN_THREADS / 64; ++w) b += (double)wsum[w];
        partials[blockIdx.x] = b;
    }
}

__global__ void orl_final_kernel(const double* __restrict__ partials, int nb,
                                 float* __restrict__ out) {
    double v = 0.0;
    for (int i = threadIdx.x; i < nb; i += blockDim.x) v += partials[i];
    #pragma unroll
    for (int off = 32; off; off >>= 1) v += __shfl_xor(v, off);
    __shared__ double sm[4];
    const int lane = threadIdx.x & 63, wid = threadIdx.x >> 6;
    if (lane == 0) sm[wid] = v;
    __syncthreads();
    if (threadIdx.x == 0) out[0] = (float)(sm[0] + sm[1] + sm[2] + sm[3]);
}

extern "C" void kernel_launch(void* const* d_in, const int* in_sizes, int n_in,
                              void* d_out, int out_size, void* d_ws, size_t ws_size,
                              hipStream_t stream) {
    const float* logits = (const float*)d_in[0];
    const int*   tgt    = (const int*)d_in[1];
    const int*   sub    = (const int*)d_in[2];
    const int n = in_sizes[1];

    int*    counts   = (int*)d_ws;
    double* partials = (double*)((char*)d_ws + 8192);
    float*  out      = (float*)d_out;

    orl_zero_kernel<<<1, NGRP, 0, stream>>>(counts);
    orl_hist_kernel<<<HIST_BLOCKS, HIST_THREADS, 0, stream>>>(tgt, sub, counts, n / 4);
    orl_main_kernel<<<MAIN_BLOCKS, MAIN_THREADS, 0, stream>>>(logits, tgt, sub, counts, partials, n >> 3);
    orl_final_kernel<<<1, 256, 0, stream>>>(partials, MAIN_BLOCKS, out);
}